// Round 5
// baseline (119.446 us; speedup 1.0000x reference)
//
#include <hip/hip_runtime.h>

// Chamfer distance K=1 NN, both directions. N=4, P1=P2=8192, D=3, fp32.
//
// Selection vs reporting split:
//   - Selection key (main loop), per target t and query p:
//       d = fma(a_t, px, s_t); d = fma(b_t, py, d); d = fma(c_t, pz, d)
//     with per-point precomputed (a,b,c,s) = (-2x,-2y,-2z,||p||^2).
//     u = d2 - sp up to ~1ulp reordering; argmin unaffected (runner-up
//     gaps >= 1e-4 >> 1e-7 perturbation).
//   - Reported value (rescan of winning 16-target block, from GLOBAL):
//     exact reference numerics, bitwise numpy fp32:
//       dot = ((px*qx)+(py*qy))+(pz*qz);  t = fmaf(-2, dot, sp+sq)
//     ascending strict < -> first-occurrence argmin tie-break.
//
// Round-4 lesson: wave-uniform s_load streaming thrashes the scalar L1
// (64 KB/block/pass through a tiny sK$; VALUBusy capped ~63% at both 16
// and 32 waves/CU). This version stages the half-cloud in LDS once and
// streams targets via ds_read_b64 broadcast (uniform address, conflict-
// free), which also kills the per-pair SGPR->VGPR movs. Reduction arrays
// reuse the target LDS after a barrier -> 64 KB/block, 2 blocks/CU.
// Register discipline: __launch_bounds__(1024,4) (cap 128), lean live set.
//
// Structure:
//   prep : SoA [A|B|C|S] (65536 each) in ws; A=-2x etc, S=((x*x)+(y*y))+(z*z).
//          Queries recover px = -0.5f*A[q] (exact).
//   nn   : 512 blocks x 1024 thr = 16 waves. Block = 256 queries (4 per
//          lane) x half target cloud staged in LDS; wave w scans LDS
//          segment [w*256, +256), 16 targets/iter shared by 4 query
//          chains, pm-fold min + min3 tree, winning-iter tracking, exact
//          global dwordx4 rescan per query, LDS (reused) reduce across
//          16 waves -> per-(block,query) partial. ws footprint = 2 MB.
//   merge: 65536 thr, combine the 2 half-cloud partials per query
//          (strict <: ties keep half 0 = smaller indices), write out.

typedef float v2f __attribute__((ext_vector_type(2)));
typedef float v4f __attribute__((ext_vector_type(4)));

#define NPTS 32768
#define TSEG 256
#define UN 16
#define Q 4

// ws float offsets (total 524288 floats = 2 MB)
#define OFF_A 0
#define OFF_B 65536
#define OFF_C 131072
#define OFF_S 196608
#define OFF_PV 262144
#define OFF_PI 393216

__device__ __forceinline__ float min3f(float a, float b, float c) {
    float d;
    asm("v_min3_f32 %0, %1, %2, %3" : "=v"(d) : "v"(a), "v"(b), "v"(c));
    return d;
}

__global__ __launch_bounds__(256) void chamfer_prep(const float* __restrict__ x,
                                                    const float* __restrict__ y,
                                                    float* __restrict__ ws) {
#pragma clang fp contract(off)
    int i = blockIdx.x * 256 + threadIdx.x;     // 0..65535
    const float* src = (i < NPTS) ? x : y;
    int j = (i < NPTS) ? i : (i - NPTS);
    float a = src[j * 3 + 0];
    float b = src[j * 3 + 1];
    float c = src[j * 3 + 2];
    ws[OFF_A + i] = -2.0f * a;                  // exact
    ws[OFF_B + i] = -2.0f * b;
    ws[OFF_C + i] = -2.0f * c;
    ws[OFF_S + i] = ((a * a) + (b * b)) + (c * c);  // bitwise numpy order
}

__global__ __launch_bounds__(1024, 4) void chamfer_nn(const float* __restrict__ ws,
                                                      float* __restrict__ pv,
                                                      int* __restrict__ pix) {
#pragma clang fp contract(off)
    // 64 KB LDS: targets [sA|sB|sC|sS] during scan; reused as sval/sidx
    // for the cross-wave reduction (rescan reads global, so targets are
    // dead before reuse; barriers separate the phases).
    __shared__ __align__(16) float smem[16384];

    int b   = blockIdx.x;            // 0..511   (dir<<8 | n<<6 | qg<<1 | sh)
    int dir = b >> 8;                // 0: x->y, 1: y->x
    int r   = b & 255;
    int n   = r >> 6;                // batch 0..3
    int r2  = r & 63;
    int qg  = r2 >> 1;               // query group of 256 (0..31)
    int sh  = r2 & 1;                // target half
    int tid  = threadIdx.x;
    int lane = tid & 63;
    int seg  = tid >> 6;             // wave id 0..15

    const float* A = ws + OFF_A;
    const float* B = ws + OFF_B;
    const float* C = ws + OFF_C;
    const float* S = ws + OFF_S;

    int qbase  = (dir ? NPTS : 0) + n * 8192 + qg * 256;
    int tcbase = (dir ? 0 : NPTS) + n * 8192;          // target cloud base
    int hbase  = tcbase + sh * 4096;                   // half base (16-aligned)
    int tbase  = hbase + seg * TSEG;                   // this wave's segment

    // Stage half cloud into LDS: 4096 targets x 4 arrays = 64 KB.
    float* sA = smem;
    float* sB = smem + 4096;
    float* sC = smem + 8192;
    float* sS = smem + 12288;
    {
        const v4f* gA = (const v4f*)(A + hbase);
        const v4f* gB = (const v4f*)(B + hbase);
        const v4f* gC = (const v4f*)(C + hbase);
        const v4f* gS = (const v4f*)(S + hbase);
        ((v4f*)sA)[tid] = gA[tid];
        ((v4f*)sB)[tid] = gB[tid];
        ((v4f*)sC)[tid] = gC[tid];
        ((v4f*)sS)[tid] = gS[tid];
    }

    // per-slot query broadcast pairs (slot q -> query qbase + q*64 + lane)
    v2f px2[Q], py2[Q], pz2[Q];
#pragma unroll
    for (int q = 0; q < Q; ++q) {
        int qi = qbase + q * 64 + lane;
        float ax = -0.5f * A[qi];    // exact recovery of original coords
        float ay = -0.5f * B[qi];
        float az = -0.5f * C[qi];
        px2[q].x = ax; px2[q].y = ax;
        py2[q].x = ay; py2[q].y = ay;
        pz2[q].x = az; pz2[q].y = az;
    }

    __syncthreads();                 // staging complete

    const v2f* sA2 = (const v2f*)sA;
    const v2f* sB2 = (const v2f*)sB;
    const v2f* sC2 = (const v2f*)sC;
    const v2f* sS2 = (const v2f*)sS;

    float best[Q];
    int   bblk[Q];
#pragma unroll
    for (int q = 0; q < Q; ++q) { best[q] = __builtin_inff(); bblk[q] = 0; }

    int lbase = seg * (TSEG / 2);    // v2f index of wave's segment in LDS
    for (int blk = 0; blk < TSEG / UN; ++blk) {
        int lp0 = lbase + blk * (UN / 2);
        float pm[Q][4];                                 // 4 running mins/query
#pragma unroll
        for (int i = 0; i < UN / 2; ++i) {
            v2f av = sA2[lp0 + i];   // uniform addr -> LDS broadcast
            v2f bv = sB2[lp0 + i];
            v2f cv = sC2[lp0 + i];
            v2f sv = sS2[lp0 + i];
#pragma unroll
            for (int q = 0; q < Q; ++q) {
                v2f d = __builtin_elementwise_fma(av, px2[q], sv);
                d = __builtin_elementwise_fma(bv, py2[q], d);
                d = __builtin_elementwise_fma(cv, pz2[q], d);
                float f = fminf(d.x, d.y);
                if ((i & 1) == 0) pm[q][i >> 1] = f;
                else              pm[q][i >> 1] = fminf(pm[q][i >> 1], f);
            }
        }
#pragma unroll
        for (int q = 0; q < Q; ++q) {
            float m = fminf(min3f(pm[q][0], pm[q][1], pm[q][2]), pm[q][3]);
            if (m < best[q]) { best[q] = m; bblk[q] = blk; }  // strict <
        }
    }

    // Exact rescan of each winning 16-target block (GLOBAL, reference
    // numerics). Ascending + strict < -> smallest index on exact-t ties.
    const v4f* A4 = (const v4f*)A;
    const v4f* B4 = (const v4f*)B;
    const v4f* C4 = (const v4f*)C;
    const v4f* S4 = (const v4f*)S;

    float rbt[Q];
    int   rbi[Q];
#pragma unroll
    for (int q = 0; q < Q; ++q) {
        int qi = qbase + q * 64 + lane;
        float sp = S[qi];
        float px = px2[q].x, py = py2[q].x, pz = pz2[q].x;
        int t0v = tbase + bblk[q] * UN;                // 16-aligned
        int q4 = t0v >> 2;
        float bt = __builtin_inff();
        int bi = t0v;
#pragma unroll
        for (int c = 0; c < 4; ++c) {
            v4f qa = A4[q4 + c], qb = B4[q4 + c], qc = C4[q4 + c], qs = S4[q4 + c];
#pragma unroll
            for (int j = 0; j < 4; ++j) {
                float qx = -0.5f * qa[j], qy = -0.5f * qb[j], qz = -0.5f * qc[j];
                float dot = ((px * qx) + (py * qy)) + (pz * qz);
                float t   = fmaf(-2.0f, dot, sp + qs[j]);
                if (t < bt) { bt = t; bi = t0v + c * 4 + j; }
            }
        }
        rbt[q] = bt;
        rbi[q] = bi;
    }

    // Reuse target LDS for the cross-wave reduction.
    __syncthreads();                 // everyone done reading sA..sS
    float* sval = smem;              // 4096 floats (bytes 0..16K)
    int*   sidx = (int*)(smem + 4096);  // 4096 ints (bytes 16K..32K)
#pragma unroll
    for (int q = 0; q < Q; ++q) {
        sval[seg * 256 + q * 64 + lane] = rbt[q];
        sidx[seg * 256 + q * 64 + lane] = rbi[q];
    }
    __syncthreads();

    // 16 waves x 256 queries; explicit index tie-break -> smallest index.
    if (tid < 256) {
        int t = tid;
        float bv = sval[t];
        int   bi = sidx[t];
#pragma unroll
        for (int w = 1; w < 16; ++w) {
            float v  = sval[w * 256 + t];
            int   i2 = sidx[w * 256 + t];
            if (v < bv || (v == bv && i2 < bi)) { bv = v; bi = i2; }
        }
        pv[b * 256 + t]  = bv;
        pix[b * 256 + t] = bi - tcbase;   // local target index 0..8191
    }
}

__global__ __launch_bounds__(256) void chamfer_merge(const float* __restrict__ pv,
                                                     const int* __restrict__ pix,
                                                     float* __restrict__ out) {
    int g = blockIdx.x * 256 + threadIdx.x;   // 0..65535
    int dir = g >> 15;
    int w   = g & 32767;
    int n   = w >> 13;
    int v   = w & 8191;
    int qg  = v >> 8;
    int qi  = v & 255;

    int b0 = ((dir * 4 + n) * 32 + qg) * 2;   // nn block id with sh=0
    int i0 = b0 * 256 + qi;
    int i1 = i0 + 256;                         // sh=1 partial

    float v0 = pv[i0], v1 = pv[i1];
    int   j0 = pix[i0], j1 = pix[i1];
    float bv; int bi;
    if (v1 < v0) { bv = v1; bi = j1; }         // ties -> half 0 (smaller idx)
    else         { bv = v0; bi = j0; }

    int o = n * 8192 + qg * 256 + qi;
    int distoff = dir ? 32768 : 0;
    int idxoff  = dir ? 98304 : 65536;
    out[distoff + o] = bv;
    out[idxoff + o]  = (float)bi;
}

extern "C" void kernel_launch(void* const* d_in, const int* in_sizes, int n_in,
                              void* d_out, int out_size, void* d_ws, size_t ws_size,
                              hipStream_t stream) {
    const float* x = (const float*)d_in[0];
    const float* y = (const float*)d_in[1];
    float* ws  = (float*)d_ws;
    float* out = (float*)d_out;

    chamfer_prep<<<256, 256, 0, stream>>>(x, y, ws);
    chamfer_nn<<<512, 1024, 0, stream>>>(ws, ws + OFF_PV, (int*)(ws + OFF_PI));
    chamfer_merge<<<256, 256, 0, stream>>>(ws + OFF_PV, (const int*)(ws + OFF_PI), out);
}